// Round 1
// baseline (3217.039 us; speedup 1.0000x reference)
//
#include <hip/hip_runtime.h>
#include <hip/hip_bf16.h>
#include <stdint.h>

// QM9 encoder: lin0 -> (NNConv + GRU) x3 -> Set2Set x3 -> lin1
// N=50000 nodes, E=100000 edges, D=64, B=2500 graphs.
// Strategy: edge-net weights ew=[E,64,64] computed ONCE via bf16 MFMA GEMM,
// stored bf16 in ws (819MB); per-layer msg = gather/apply/scatter (fp32 acc);
// node update (root GEMM + GRU gates) fused into one MFMA kernel.
// Falls back to chunked ew recompute if ws_size is small.

#define N_NODES 50000
#define N_EDGES 100000
#define NGRAPH  2500
#define FIN     11
#define EATT    5

typedef __attribute__((ext_vector_type(8))) short short8;
typedef __attribute__((ext_vector_type(4))) float f32x4;

__device__ __forceinline__ short8 zero8(){ short8 z = {0,0,0,0,0,0,0,0}; return z; }

__device__ __forceinline__ unsigned short f2bf(float x){
  unsigned u = __float_as_uint(x);
  u += 0x7FFFu + ((u >> 16) & 1u);   // RNE
  return (unsigned short)(u >> 16);
}
__device__ __forceinline__ float bf2f(unsigned short s){
  return __uint_as_float(((unsigned)s) << 16);
}
__device__ __forceinline__ float sigm(float x){ return 1.0f/(1.0f+__expf(-x)); }
// order-preserving float<->uint encode for atomicMax
__device__ __forceinline__ unsigned encf(float x){
  unsigned u = __float_as_uint(x);
  return (u & 0x80000000u) ? ~u : (u | 0x80000000u);
}
__device__ __forceinline__ float decf(unsigned e){
  unsigned u = (e & 0x80000000u) ? (e ^ 0x80000000u) : ~e;
  return __uint_as_float(u);
}

// ---- weight conversion to bf16 (mlp2, root, gru_ih, gru_hh) ----
__global__ void k_wcvt(const float* __restrict__ mlp2w, const float* __restrict__ rootw,
                       const float* __restrict__ wih, const float* __restrict__ whh,
                       unsigned short* __restrict__ mlp2b, unsigned short* __restrict__ rootb,
                       unsigned short* __restrict__ wihb, unsigned short* __restrict__ whhb){
  int i = blockIdx.x*256 + threadIdx.x;
  if (i < 524288) mlp2b[i] = f2bf(mlp2w[i]);
  else if (i < 528384) rootb[i-524288] = f2bf(rootw[i-524288]);
  else if (i < 540672) wihb[i-528384] = f2bf(wih[i-528384]);
  else if (i < 552960) whhb[i-540672] = f2bf(whh[i-540672]);
}

// ---- out = relu(x @ lin0_w^T + b), also bf16 shadow ----
__global__ void k_lin0(const float* __restrict__ x, const float* __restrict__ w,
                       const float* __restrict__ b, float* __restrict__ out,
                       unsigned short* __restrict__ outb){
  int t = blockIdx.x*256 + threadIdx.x;
  int n = t >> 6, o = t & 63;
  if (n >= N_NODES) return;
  float s = b[o];
  #pragma unroll
  for (int f = 0; f < FIN; ++f) s += x[n*FIN+f]*w[o*FIN+f];
  s = fmaxf(s, 0.f);
  out[(size_t)n*64+o] = s; outb[(size_t)n*64+o] = f2bf(s);
}

// ---- hid = relu(edge_attr @ mlp1_w^T + b), bf16 ----
__global__ void k_mlp1(const float* __restrict__ ea, const float* __restrict__ w,
                       const float* __restrict__ b, unsigned short* __restrict__ hidb){
  int t = blockIdx.x*256 + threadIdx.x;
  int e = t >> 7, j = t & 127;
  if (e >= N_EDGES) return;
  float s = b[j];
  #pragma unroll
  for (int a = 0; a < EATT; ++a) s += ea[e*EATT+a]*w[j*EATT+a];
  hidb[(size_t)e*128+j] = f2bf(fmaxf(s,0.f));
}

__global__ void k_deg(const int* __restrict__ dst, float* __restrict__ deg){
  int e = blockIdx.x*256 + threadIdx.x;
  if (e < N_EDGES) atomicAdd(&deg[dst[e]], 1.0f);
}
__global__ void k_deginv(float* deg){
  int n = blockIdx.x*256 + threadIdx.x;
  if (n < N_NODES) deg[n] = 1.0f / fmaxf(deg[n], 1.0f);
}

// ---- ew[rows,4096] = hid[e0+rows,128] @ mlp2_w^T + b2   (bf16 MFMA) ----
// block: 256 thr = 4 waves; each wave covers all 64 rows of the m-tile and a
// 1024-wide n-range (no cross-wave sharing -> no barriers).
__global__ __launch_bounds__(256) void k_mlp2(const unsigned short* __restrict__ hidb,
                       const unsigned short* __restrict__ w2b, const float* __restrict__ b2,
                       unsigned short* __restrict__ ew, int e0, int rows){
  int mt = blockIdx.x;
  int wave = threadIdx.x >> 6;
  int l = threadIdx.x & 63;
  int lm = l & 15, g = l >> 4;
  short8 afr[4][4];
  #pragma unroll
  for (int ms = 0; ms < 4; ++ms){
    int r = mt*64 + ms*16 + lm;
    bool ok = (r < rows);
    size_t ge = (size_t)(e0 + r);
    #pragma unroll
    for (int kk = 0; kk < 4; ++kk)
      afr[ms][kk] = ok ? *(const short8*)(hidb + ge*128 + kk*32 + 8*g) : zero8();
  }
  for (int nt4 = 0; nt4 < 16; ++nt4){
    int nbase = wave*1024 + nt4*64;
    f32x4 acc[4][4];
    #pragma unroll
    for (int ms=0; ms<4; ++ms){
      #pragma unroll
      for (int t=0; t<4; ++t){ f32x4 z = {0.f,0.f,0.f,0.f}; acc[ms][t] = z; }
    }
    #pragma unroll
    for (int t = 0; t < 4; ++t){
      int n0 = nbase + t*16;
      #pragma unroll
      for (int kk = 0; kk < 4; ++kk){
        short8 bfr = *(const short8*)(w2b + (size_t)(n0+lm)*128 + kk*32 + 8*g);
        #pragma unroll
        for (int ms = 0; ms < 4; ++ms)
          acc[ms][t] = __builtin_amdgcn_mfma_f32_16x16x32_bf16(afr[ms][kk], bfr, acc[ms][t], 0,0,0);
      }
    }
    #pragma unroll
    for (int t = 0; t < 4; ++t){
      float bias = b2[nbase + t*16 + lm];
      #pragma unroll
      for (int ms = 0; ms < 4; ++ms){
        #pragma unroll
        for (int i = 0; i < 4; ++i){
          int r = mt*64 + ms*16 + 4*g + i;
          if (r < rows)
            ew[(size_t)r*4096 + nbase + t*16 + lm] = f2bf(acc[ms][t][i] + bias);
        }
      }
    }
  }
}

// ---- msg scatter: agg[dst] += out[src] @ ew_e ----
__global__ void k_msg(const float* __restrict__ out, const unsigned short* __restrict__ ew,
                      const int* __restrict__ src, const int* __restrict__ dst,
                      float* __restrict__ agg, int e0, int rows){
  __shared__ float os[4][64];
  int eg = blockIdx.x*4 + (threadIdx.x>>6);
  int o = threadIdx.x & 63;
  int eloc = threadIdx.x>>6;
  bool ok = eg < rows;
  int e = e0 + eg;
  int sn = ok ? src[e] : 0;
  os[eloc][o] = ok ? out[(size_t)sn*64+o] : 0.f;
  __syncthreads();
  if (!ok) return;
  float s = 0.f;
  const unsigned short* ewp = ew + (size_t)eg*4096 + o;
  #pragma unroll 8
  for (int i = 0; i < 64; ++i) s += os[eloc][i] * bf2f(ewp[i*64]);
  atomicAdd(&agg[(size_t)dst[e]*64+o], s);
}

// ---- fused: m = relu(agg/deg + out@root^T + cb); GRU(m, h=out) -> out ----
__global__ __launch_bounds__(256) void k_update(float* __restrict__ out, unsigned short* __restrict__ outb,
        const float* __restrict__ agg, const float* __restrict__ deginv,
        const unsigned short* __restrict__ rootb, const float* __restrict__ convb,
        const unsigned short* __restrict__ wihb, const unsigned short* __restrict__ whhb,
        const float* __restrict__ bih, const float* __restrict__ bhh){
  __shared__ unsigned short ms_[4][1024];   // per-wave 16x64 bf16 m-tile (XOR-swizzled)
  int wave = threadIdx.x >> 6;
  int l = threadIdx.x & 63;
  int lm = l & 15, g = l >> 4;
  int m0 = blockIdx.x*64 + wave*16;
  short8 ah[2];
  {
    int r = m0 + lm; bool ok = r < N_NODES;
    #pragma unroll
    for (int kk = 0; kk < 2; ++kk)
      ah[kk] = ok ? *(const short8*)(outb + (size_t)r*64 + kk*32 + 8*g) : zero8();
  }
  // phase 1: m tile
  #pragma unroll
  for (int nt = 0; nt < 4; ++nt){
    f32x4 acc = {0.f,0.f,0.f,0.f};
    #pragma unroll
    for (int kk = 0; kk < 2; ++kk){
      short8 b = *(const short8*)(rootb + (size_t)(nt*16+lm)*64 + kk*32 + 8*g);
      acc = __builtin_amdgcn_mfma_f32_16x16x32_bf16(ah[kk], b, acc, 0,0,0);
    }
    int c = nt*16 + lm;
    #pragma unroll
    for (int i = 0; i < 4; ++i){
      int lr = 4*g + i, r = m0 + lr;
      float v = 0.f;
      if (r < N_NODES) v = fmaxf(acc[i] + agg[(size_t)r*64+c]*deginv[r] + convb[c], 0.f);
      ms_[wave][(lr*64 + c) ^ ((lr&7)<<3)] = f2bf(v);
    }
  }
  __syncthreads();
  // phase 2: gi = m@Wih^T, gh = h@Whh^T (12 col-tiles of 16 over 192)
  short8 am[2];
  #pragma unroll
  for (int kk = 0; kk < 2; ++kk)
    am[kk] = *(const short8*)(&ms_[wave][(lm*64 + kk*32 + 8*g) ^ ((lm&7)<<3)]);
  f32x4 accg[12], acch[12];
  #pragma unroll
  for (int nt = 0; nt < 12; ++nt){ f32x4 z = {0.f,0.f,0.f,0.f}; accg[nt]=z; acch[nt]=z; }
  #pragma unroll
  for (int nt = 0; nt < 12; ++nt){
    #pragma unroll
    for (int kk = 0; kk < 2; ++kk){
      short8 bg = *(const short8*)(wihb + (size_t)(nt*16+lm)*64 + kk*32 + 8*g);
      accg[nt] = __builtin_amdgcn_mfma_f32_16x16x32_bf16(am[kk], bg, accg[nt], 0,0,0);
      short8 bh = *(const short8*)(whhb + (size_t)(nt*16+lm)*64 + kk*32 + 8*g);
      acch[nt] = __builtin_amdgcn_mfma_f32_16x16x32_bf16(ah[kk], bh, acch[nt], 0,0,0);
    }
  }
  // phase 3: gates (torch order r,z,n) + blend
  #pragma unroll
  for (int nt = 0; nt < 4; ++nt){
    int c = nt*16 + lm;
    #pragma unroll
    for (int i = 0; i < 4; ++i){
      int r = m0 + 4*g + i;
      if (r < N_NODES){
        float ir = accg[nt][i]   + bih[c],     hr = acch[nt][i]   + bhh[c];
        float iz = accg[nt+4][i] + bih[64+c],  hz = acch[nt+4][i] + bhh[64+c];
        float in_= accg[nt+8][i] + bih[128+c], hn = acch[nt+8][i] + bhh[128+c];
        float rr = sigm(ir+hr), zz = sigm(iz+hz);
        float nn = tanhf(in_ + rr*hn);
        float hp = out[(size_t)r*64+c];
        float hv = (1.f-zz)*nn + zz*hp;
        out[(size_t)r*64+c] = hv;
        outb[(size_t)r*64+c] = f2bf(hv);
      }
    }
  }
}

// ---- Set2Set pieces ----
__global__ void k_lstm(const float* __restrict__ qstar, float* __restrict__ hl, float* __restrict__ cl,
                       const float* __restrict__ wih, const float* __restrict__ whh,
                       const float* __restrict__ bih, const float* __restrict__ bhh){
  __shared__ float qs[128], hs[64], gg[256];
  int b = blockIdx.x, t = threadIdx.x;
  if (t < 128) qs[t] = qstar[(size_t)b*128+t];
  if (t < 64)  hs[t] = hl[(size_t)b*64+t];
  __syncthreads();
  float s = bih[t] + bhh[t];
  #pragma unroll 4
  for (int k = 0; k < 128; ++k) s += qs[k]*wih[t*128+k];
  #pragma unroll 4
  for (int k = 0; k < 64; ++k)  s += hs[k]*whh[t*64+k];
  gg[t] = s;
  __syncthreads();
  if (t < 64){
    float i = sigm(gg[t]), f = sigm(gg[64+t]), g = tanhf(gg[128+t]), o = sigm(gg[192+t]);
    float c = f*cl[(size_t)b*64+t] + i*g;
    float h = o*tanhf(c);
    cl[(size_t)b*64+t] = c; hl[(size_t)b*64+t] = h;
  }
}

__global__ void k_att_e(const float* __restrict__ out, const float* __restrict__ hl,
                        const int* __restrict__ batch, float* __restrict__ ebuf,
                        unsigned* __restrict__ emaxu){
  int n = blockIdx.x*4 + (threadIdx.x>>6);
  int o = threadIdx.x & 63;
  if (n >= N_NODES) return;
  int b = batch[n];
  float p = out[(size_t)n*64+o] * hl[(size_t)b*64+o];
  #pragma unroll
  for (int d = 32; d >= 1; d >>= 1) p += __shfl_down(p, d, 64);
  if (o == 0){ ebuf[n] = p; atomicMax(&emaxu[b], encf(p)); }
}

__global__ void k_att_a(const float* __restrict__ ebuf, const int* __restrict__ batch,
                        const unsigned* __restrict__ emaxu, float* __restrict__ abuf,
                        float* __restrict__ asum){
  int n = blockIdx.x*256 + threadIdx.x;
  if (n >= N_NODES) return;
  int b = batch[n];
  float aa = __expf(ebuf[n] - decf(emaxu[b]));
  abuf[n] = aa;
  atomicAdd(&asum[b], aa);
}

__global__ void k_att_r(const float* __restrict__ out, const float* __restrict__ abuf,
                        const float* __restrict__ asum, const int* __restrict__ batch,
                        float* __restrict__ rbuf){
  int n = blockIdx.x*4 + (threadIdx.x>>6);
  int o = threadIdx.x & 63;
  if (n >= N_NODES) return;
  int b = batch[n];
  float w = abuf[n] / asum[b];
  atomicAdd(&rbuf[(size_t)b*64+o], w * out[(size_t)n*64+o]);
}

__global__ void k_qstar(const float* __restrict__ hl, const float* __restrict__ rbuf,
                        float* __restrict__ qstar){
  int t = blockIdx.x*256 + threadIdx.x;
  if (t >= NGRAPH*128) return;
  int b = t >> 7, c = t & 127;
  qstar[t] = (c < 64) ? hl[(size_t)b*64+c] : rbuf[(size_t)b*64 + c - 64];
}

__global__ void k_lin1(const float* __restrict__ qstar, const float* __restrict__ w,
                       const float* __restrict__ b, float* __restrict__ outp){
  __shared__ float qs[128];
  int bg = blockIdx.x, o = threadIdx.x;   // 64 threads
  qs[o] = qstar[(size_t)bg*128+o];
  qs[64+o] = qstar[(size_t)bg*128+64+o];
  __syncthreads();
  float s = b[o];
  #pragma unroll 4
  for (int k = 0; k < 128; ++k) s += qs[k]*w[o*128+k];
  outp[(size_t)bg*64+o] = fmaxf(s, 0.f);
}

extern "C" void kernel_launch(void* const* d_in, const int* in_sizes, int n_in,
                              void* d_out, int out_size, void* d_ws, size_t ws_size,
                              hipStream_t stream){
  (void)in_sizes; (void)n_in; (void)out_size;
  const float* x      = (const float*)d_in[0];
  const float* eattr  = (const float*)d_in[1];
  const float* lin0w  = (const float*)d_in[2];
  const float* lin0b  = (const float*)d_in[3];
  const float* mlp1w  = (const float*)d_in[4];
  const float* mlp1b  = (const float*)d_in[5];
  const float* mlp2w  = (const float*)d_in[6];
  const float* mlp2b_ = (const float*)d_in[7];
  const float* rootw  = (const float*)d_in[8];
  const float* convb  = (const float*)d_in[9];
  const float* gwih   = (const float*)d_in[10];
  const float* gwhh   = (const float*)d_in[11];
  const float* gbih   = (const float*)d_in[12];
  const float* gbhh   = (const float*)d_in[13];
  const float* lwih   = (const float*)d_in[14];
  const float* lwhh   = (const float*)d_in[15];
  const float* lbih   = (const float*)d_in[16];
  const float* lbhh   = (const float*)d_in[17];
  const float* lin1w  = (const float*)d_in[18];
  const float* lin1b  = (const float*)d_in[19];
  const int*   eidx   = (const int*)d_in[20];
  const int*   batch  = (const int*)d_in[21];
  const int* srcp = eidx;
  const int* dstp = eidx + N_EDGES;

  char* ws = (char*)d_ws;
  size_t off = 0;
  auto take = [&](size_t bytes)->char*{
    char* p = ws + off; off = (off + bytes + 255) & ~(size_t)255; return p;
  };
  float* out   = (float*)take((size_t)N_NODES*64*4);
  unsigned short* outb = (unsigned short*)take((size_t)N_NODES*64*2);
  unsigned short* hidb = (unsigned short*)take((size_t)N_EDGES*128*2);
  float* agg   = (float*)take((size_t)N_NODES*64*4);
  float* deg   = (float*)take((size_t)N_NODES*4);
  unsigned short* w2b   = (unsigned short*)take((size_t)524288*2);
  unsigned short* rootb = (unsigned short*)take(4096*2);
  unsigned short* wihb  = (unsigned short*)take(12288*2);
  unsigned short* whhb  = (unsigned short*)take(12288*2);
  float* ebuf  = (float*)take((size_t)N_NODES*4);
  float* abuf  = (float*)take((size_t)N_NODES*4);
  char* z1 = take((size_t)NGRAPH*4 + NGRAPH*4 + (size_t)NGRAPH*64*4);
  unsigned* emaxu = (unsigned*)z1;
  float* asum = (float*)(z1 + NGRAPH*4);
  float* rbuf = (float*)(z1 + NGRAPH*8);
  size_t z1bytes = (size_t)NGRAPH*4 + NGRAPH*4 + (size_t)NGRAPH*64*4;
  char* z2 = take((size_t)NGRAPH*64*4*2 + (size_t)NGRAPH*128*4);
  float* hl = (float*)z2;
  float* cl = (float*)(z2 + (size_t)NGRAPH*64*4);
  float* qstar = (float*)(z2 + (size_t)NGRAPH*64*4*2);
  size_t z2bytes = (size_t)NGRAPH*64*4*2 + (size_t)NGRAPH*128*4;

  size_t remain = (ws_size > off) ? (ws_size - off) : 0;
  long long cap = (long long)(remain / ((size_t)4096*2));
  int chunk = (cap >= N_EDGES) ? N_EDGES : (int)(cap & ~63LL);
  if (chunk < 64) chunk = 64;
  unsigned short* ew = (unsigned short*)(ws + off);
  bool full = (chunk >= N_EDGES);

  hipMemsetAsync(deg, 0, (size_t)N_NODES*4, stream);
  hipMemsetAsync(z2, 0, z2bytes, stream);
  k_wcvt<<<2160,256,0,stream>>>(mlp2w, rootw, gwih, gwhh, w2b, rootb, wihb, whhb);
  k_lin0<<<12500,256,0,stream>>>(x, lin0w, lin0b, out, outb);
  k_mlp1<<<50000,256,0,stream>>>(eattr, mlp1w, mlp1b, hidb);
  k_deg<<<(N_EDGES+255)/256,256,0,stream>>>(dstp, deg);
  k_deginv<<<(N_NODES+255)/256,256,0,stream>>>(deg);
  if (full)
    k_mlp2<<<(N_EDGES+63)/64,256,0,stream>>>(hidb, w2b, mlp2b_, ew, 0, N_EDGES);

  for (int layer = 0; layer < 3; ++layer){
    hipMemsetAsync(agg, 0, (size_t)N_NODES*64*4, stream);
    if (full){
      k_msg<<<(N_EDGES+3)/4,256,0,stream>>>(out, ew, srcp, dstp, agg, 0, N_EDGES);
    } else {
      for (int e0 = 0; e0 < N_EDGES; e0 += chunk){
        int rows = (N_EDGES - e0 < chunk) ? (N_EDGES - e0) : chunk;
        k_mlp2<<<(rows+63)/64,256,0,stream>>>(hidb, w2b, mlp2b_, ew, e0, rows);
        k_msg<<<(rows+3)/4,256,0,stream>>>(out, ew, srcp, dstp, agg, e0, rows);
      }
    }
    k_update<<<(N_NODES+63)/64,256,0,stream>>>(out, outb, agg, deg, rootb, convb,
                                               wihb, whhb, gbih, gbhh);
  }

  for (int step = 0; step < 3; ++step){
    hipMemsetAsync(z1, 0, z1bytes, stream);
    k_lstm<<<NGRAPH,256,0,stream>>>(qstar, hl, cl, lwih, lwhh, lbih, lbhh);
    k_att_e<<<(N_NODES+3)/4,256,0,stream>>>(out, hl, batch, ebuf, emaxu);
    k_att_a<<<(N_NODES+255)/256,256,0,stream>>>(ebuf, batch, emaxu, abuf, asum);
    k_att_r<<<(N_NODES+3)/4,256,0,stream>>>(out, abuf, asum, batch, rbuf);
    k_qstar<<<(NGRAPH*128+255)/256,256,0,stream>>>(hl, rbuf, qstar);
  }
  k_lin1<<<NGRAPH,64,0,stream>>>(qstar, lin1w, lin1b, (float*)d_out);
}

// Round 2
// 3175.581 us; speedup vs baseline: 1.0131x; 1.0131x over previous
//
#include <hip/hip_runtime.h>
#include <hip/hip_bf16.h>
#include <stdint.h>

// QM9 encoder: lin0 -> (NNConv + GRU) x3 -> Set2Set x3 -> lin1
// N=50000, E=100000, D=64, B=2500.
// ew=[E,64,64] bf16 computed once (MFMA GEMM, C^T operand-swap for vectorized
// 8B stores), read 3x by wave-per-edge vectorized msg kernel (16B/lane loads).

#define N_NODES 50000
#define N_EDGES 100000
#define NGRAPH  2500
#define FIN     11
#define EATT    5

typedef __attribute__((ext_vector_type(8))) short short8;
typedef __attribute__((ext_vector_type(4))) float f32x4;

__device__ __forceinline__ short8 zero8(){ short8 z = {0,0,0,0,0,0,0,0}; return z; }

__device__ __forceinline__ unsigned short f2bf(float x){
  unsigned u = __float_as_uint(x);
  u += 0x7FFFu + ((u >> 16) & 1u);   // RNE
  return (unsigned short)(u >> 16);
}
__device__ __forceinline__ float bf2f(unsigned short s){
  return __uint_as_float(((unsigned)s) << 16);
}
__device__ __forceinline__ float sigm(float x){ return 1.0f/(1.0f+__expf(-x)); }
__device__ __forceinline__ unsigned encf(float x){
  unsigned u = __float_as_uint(x);
  return (u & 0x80000000u) ? ~u : (u | 0x80000000u);
}
__device__ __forceinline__ float decf(unsigned e){
  unsigned u = (e & 0x80000000u) ? (e ^ 0x80000000u) : ~e;
  return __uint_as_float(u);
}

// ---- weight conversion to bf16 ----
__global__ void k_wcvt(const float* __restrict__ mlp2w, const float* __restrict__ rootw,
                       const float* __restrict__ wih, const float* __restrict__ whh,
                       unsigned short* __restrict__ mlp2b, unsigned short* __restrict__ rootb,
                       unsigned short* __restrict__ wihb, unsigned short* __restrict__ whhb){
  int i = blockIdx.x*256 + threadIdx.x;
  if (i < 524288) mlp2b[i] = f2bf(mlp2w[i]);
  else if (i < 528384) rootb[i-524288] = f2bf(rootw[i-524288]);
  else if (i < 540672) wihb[i-528384] = f2bf(wih[i-528384]);
  else if (i < 552960) whhb[i-540672] = f2bf(whh[i-540672]);
}

// ---- out = relu(x @ lin0_w^T + b), also bf16 shadow ----
__global__ void k_lin0(const float* __restrict__ x, const float* __restrict__ w,
                       const float* __restrict__ b, float* __restrict__ out,
                       unsigned short* __restrict__ outb){
  int t = blockIdx.x*256 + threadIdx.x;
  int n = t >> 6, o = t & 63;
  if (n >= N_NODES) return;
  float s = b[o];
  #pragma unroll
  for (int f = 0; f < FIN; ++f) s += x[n*FIN+f]*w[o*FIN+f];
  s = fmaxf(s, 0.f);
  out[(size_t)n*64+o] = s; outb[(size_t)n*64+o] = f2bf(s);
}

// ---- hid = relu(edge_attr @ mlp1_w^T + b), bf16 ----
__global__ void k_mlp1(const float* __restrict__ ea, const float* __restrict__ w,
                       const float* __restrict__ b, unsigned short* __restrict__ hidb){
  int t = blockIdx.x*256 + threadIdx.x;
  int e = t >> 7, j = t & 127;
  if (e >= N_EDGES) return;
  float s = b[j];
  #pragma unroll
  for (int a = 0; a < EATT; ++a) s += ea[e*EATT+a]*w[j*EATT+a];
  hidb[(size_t)e*128+j] = f2bf(fmaxf(s,0.f));
}

__global__ void k_deg(const int* __restrict__ dst, float* __restrict__ deg){
  int e = blockIdx.x*256 + threadIdx.x;
  if (e < N_EDGES) atomicAdd(&deg[dst[e]], 1.0f);
}
__global__ void k_deginv(float* deg){
  int n = blockIdx.x*256 + threadIdx.x;
  if (n < N_NODES) deg[n] = 1.0f / fmaxf(deg[n], 1.0f);
}

// ---- ew[rows,4096] = hid @ mlp2_w^T + b2 (bf16 MFMA, C^T for packed stores) ----
// mfma(bfr, afr): D rows = W2-n (reg-contiguous!), cols = edges -> each lane
// packs 4 consecutive bf16 cols of one edge into a single 8B store.
__global__ __launch_bounds__(256) void k_mlp2(const unsigned short* __restrict__ hidb,
                       const unsigned short* __restrict__ w2b, const float* __restrict__ b2,
                       unsigned short* __restrict__ ew, int e0, int rows){
  int mt = blockIdx.x;
  int wave = threadIdx.x >> 6;
  int l = threadIdx.x & 63;
  int lm = l & 15, g = l >> 4;
  short8 afr[4][4];
  #pragma unroll
  for (int ms = 0; ms < 4; ++ms){
    int r = mt*64 + ms*16 + lm;
    bool ok = (r < rows);
    size_t ge = (size_t)(e0 + r);
    #pragma unroll
    for (int kk = 0; kk < 4; ++kk)
      afr[ms][kk] = ok ? *(const short8*)(hidb + ge*128 + kk*32 + 8*g) : zero8();
  }
  for (int nt4 = 0; nt4 < 16; ++nt4){
    int nbase = wave*1024 + nt4*64;
    f32x4 acc[4][4];
    #pragma unroll
    for (int ms=0; ms<4; ++ms){
      #pragma unroll
      for (int t=0; t<4; ++t){ f32x4 z = {0.f,0.f,0.f,0.f}; acc[ms][t] = z; }
    }
    #pragma unroll
    for (int t = 0; t < 4; ++t){
      int n0 = nbase + t*16;
      #pragma unroll
      for (int kk = 0; kk < 4; ++kk){
        short8 bfr = *(const short8*)(w2b + (size_t)(n0+lm)*128 + kk*32 + 8*g);
        #pragma unroll
        for (int ms = 0; ms < 4; ++ms)
          acc[ms][t] = __builtin_amdgcn_mfma_f32_16x16x32_bf16(bfr, afr[ms][kk], acc[ms][t], 0,0,0);
      }
    }
    #pragma unroll
    for (int t = 0; t < 4; ++t){
      int n0 = nbase + t*16 + 4*g;              // 4 consecutive cols per lane
      float4 bv = *(const float4*)(b2 + n0);
      #pragma unroll
      for (int ms = 0; ms < 4; ++ms){
        int edge = mt*64 + ms*16 + lm;
        if (edge < rows){
          unsigned short h0 = f2bf(acc[ms][t][0] + bv.x);
          unsigned short h1 = f2bf(acc[ms][t][1] + bv.y);
          unsigned short h2 = f2bf(acc[ms][t][2] + bv.z);
          unsigned short h3 = f2bf(acc[ms][t][3] + bv.w);
          uint2 p; p.x = (unsigned)h0 | ((unsigned)h1<<16);
                   p.y = (unsigned)h2 | ((unsigned)h3<<16);
          *(uint2*)(ew + (size_t)edge*4096 + n0) = p;
        }
      }
    }
  }
}

// ---- msg scatter: agg[dst] += out[src] @ ew_e  (wave per edge, 16B loads) ----
__global__ __launch_bounds__(256) void k_msg(const float* __restrict__ out,
                      const unsigned short* __restrict__ ew,
                      const int* __restrict__ src, const int* __restrict__ dst,
                      float* __restrict__ agg, int e0, int rows){
  __shared__ float os[4][64];
  int w = threadIdx.x >> 6;
  int l = threadIdx.x & 63;
  int eg = blockIdx.x*4 + w;
  bool ok = eg < rows;
  int e = e0 + eg;
  int sn = ok ? src[e] : 0;
  os[w][l] = ok ? out[(size_t)sn*64 + l] : 0.f;
  __syncthreads();
  int ih = l >> 3;     // i = ii*8 + ih
  int c8 = l & 7;      // cols c8*8 .. c8*8+7
  float acc[8] = {0,0,0,0,0,0,0,0};
  if (ok){
    const unsigned short* ewp = ew + (size_t)eg*4096 + c8*8;
    #pragma unroll
    for (int ii = 0; ii < 8; ++ii){
      int i = ii*8 + ih;
      short8 v = *(const short8*)(ewp + (size_t)i*64);
      float osv = os[w][i];
      #pragma unroll
      for (int j = 0; j < 8; ++j) acc[j] += osv * bf2f((unsigned short)v[j]);
    }
  }
  #pragma unroll
  for (int d = 8; d < 64; d <<= 1){
    #pragma unroll
    for (int j = 0; j < 8; ++j) acc[j] += __shfl_xor(acc[j], d, 64);
  }
  if (ok && ih == 0){
    float* ap = agg + (size_t)dst[e]*64 + c8*8;
    #pragma unroll
    for (int j = 0; j < 8; ++j) atomicAdd(ap + j, acc[j]);
  }
}

// ---- fused: m = relu(agg/deg + out@root^T + cb); GRU(m, h=out) -> out ----
__global__ __launch_bounds__(256) void k_update(float* __restrict__ out, unsigned short* __restrict__ outb,
        const float* __restrict__ agg, const float* __restrict__ deginv,
        const unsigned short* __restrict__ rootb, const float* __restrict__ convb,
        const unsigned short* __restrict__ wihb, const unsigned short* __restrict__ whhb,
        const float* __restrict__ bih, const float* __restrict__ bhh){
  __shared__ unsigned short ms_[4][1024];
  int wave = threadIdx.x >> 6;
  int l = threadIdx.x & 63;
  int lm = l & 15, g = l >> 4;
  int m0 = blockIdx.x*64 + wave*16;
  short8 ah[2];
  {
    int r = m0 + lm; bool ok = r < N_NODES;
    #pragma unroll
    for (int kk = 0; kk < 2; ++kk)
      ah[kk] = ok ? *(const short8*)(outb + (size_t)r*64 + kk*32 + 8*g) : zero8();
  }
  #pragma unroll
  for (int nt = 0; nt < 4; ++nt){
    f32x4 acc = {0.f,0.f,0.f,0.f};
    #pragma unroll
    for (int kk = 0; kk < 2; ++kk){
      short8 b = *(const short8*)(rootb + (size_t)(nt*16+lm)*64 + kk*32 + 8*g);
      acc = __builtin_amdgcn_mfma_f32_16x16x32_bf16(ah[kk], b, acc, 0,0,0);
    }
    int c = nt*16 + lm;
    #pragma unroll
    for (int i = 0; i < 4; ++i){
      int lr = 4*g + i, r = m0 + lr;
      float v = 0.f;
      if (r < N_NODES) v = fmaxf(acc[i] + agg[(size_t)r*64+c]*deginv[r] + convb[c], 0.f);
      ms_[wave][(lr*64 + c) ^ ((lr&7)<<3)] = f2bf(v);
    }
  }
  __syncthreads();
  short8 am[2];
  #pragma unroll
  for (int kk = 0; kk < 2; ++kk)
    am[kk] = *(const short8*)(&ms_[wave][(lm*64 + kk*32 + 8*g) ^ ((lm&7)<<3)]);
  f32x4 accg[12], acch[12];
  #pragma unroll
  for (int nt = 0; nt < 12; ++nt){ f32x4 z = {0.f,0.f,0.f,0.f}; accg[nt]=z; acch[nt]=z; }
  #pragma unroll
  for (int nt = 0; nt < 12; ++nt){
    #pragma unroll
    for (int kk = 0; kk < 2; ++kk){
      short8 bg = *(const short8*)(wihb + (size_t)(nt*16+lm)*64 + kk*32 + 8*g);
      accg[nt] = __builtin_amdgcn_mfma_f32_16x16x32_bf16(am[kk], bg, accg[nt], 0,0,0);
      short8 bh = *(const short8*)(whhb + (size_t)(nt*16+lm)*64 + kk*32 + 8*g);
      acch[nt] = __builtin_amdgcn_mfma_f32_16x16x32_bf16(ah[kk], bh, acch[nt], 0,0,0);
    }
  }
  #pragma unroll
  for (int nt = 0; nt < 4; ++nt){
    int c = nt*16 + lm;
    #pragma unroll
    for (int i = 0; i < 4; ++i){
      int r = m0 + 4*g + i;
      if (r < N_NODES){
        float ir = accg[nt][i]   + bih[c],     hr = acch[nt][i]   + bhh[c];
        float iz = accg[nt+4][i] + bih[64+c],  hz = acch[nt+4][i] + bhh[64+c];
        float in_= accg[nt+8][i] + bih[128+c], hn = acch[nt+8][i] + bhh[128+c];
        float rr = sigm(ir+hr), zz = sigm(iz+hz);
        float nn = tanhf(in_ + rr*hn);
        float hp = out[(size_t)r*64+c];
        float hv = (1.f-zz)*nn + zz*hp;
        out[(size_t)r*64+c] = hv;
        outb[(size_t)r*64+c] = f2bf(hv);
      }
    }
  }
}

// ---- Set2Set pieces ----
__global__ void k_lstm(const float* __restrict__ qstar, float* __restrict__ hl, float* __restrict__ cl,
                       const float* __restrict__ wih, const float* __restrict__ whh,
                       const float* __restrict__ bih, const float* __restrict__ bhh){
  __shared__ float qs[128], hs[64], gg[256];
  int b = blockIdx.x, t = threadIdx.x;
  if (t < 128) qs[t] = qstar[(size_t)b*128+t];
  if (t < 64)  hs[t] = hl[(size_t)b*64+t];
  __syncthreads();
  float s = bih[t] + bhh[t];
  #pragma unroll 4
  for (int k = 0; k < 128; ++k) s += qs[k]*wih[t*128+k];
  #pragma unroll 4
  for (int k = 0; k < 64; ++k)  s += hs[k]*whh[t*64+k];
  gg[t] = s;
  __syncthreads();
  if (t < 64){
    float i = sigm(gg[t]), f = sigm(gg[64+t]), g = tanhf(gg[128+t]), o = sigm(gg[192+t]);
    float c = f*cl[(size_t)b*64+t] + i*g;
    float h = o*tanhf(c);
    cl[(size_t)b*64+t] = c; hl[(size_t)b*64+t] = h;
  }
}

__global__ void k_att_e(const float* __restrict__ out, const float* __restrict__ hl,
                        const int* __restrict__ batch, float* __restrict__ ebuf,
                        unsigned* __restrict__ emaxu){
  int n = blockIdx.x*4 + (threadIdx.x>>6);
  int o = threadIdx.x & 63;
  if (n >= N_NODES) return;
  int b = batch[n];
  float p = out[(size_t)n*64+o] * hl[(size_t)b*64+o];
  #pragma unroll
  for (int d = 32; d >= 1; d >>= 1) p += __shfl_down(p, d, 64);
  if (o == 0){ ebuf[n] = p; atomicMax(&emaxu[b], encf(p)); }
}

__global__ void k_att_a(const float* __restrict__ ebuf, const int* __restrict__ batch,
                        const unsigned* __restrict__ emaxu, float* __restrict__ abuf,
                        float* __restrict__ asum){
  int n = blockIdx.x*256 + threadIdx.x;
  if (n >= N_NODES) return;
  int b = batch[n];
  float aa = __expf(ebuf[n] - decf(emaxu[b]));
  abuf[n] = aa;
  atomicAdd(&asum[b], aa);
}

__global__ void k_att_r(const float* __restrict__ out, const float* __restrict__ abuf,
                        const float* __restrict__ asum, const int* __restrict__ batch,
                        float* __restrict__ rbuf){
  int n = blockIdx.x*4 + (threadIdx.x>>6);
  int o = threadIdx.x & 63;
  if (n >= N_NODES) return;
  int b = batch[n];
  float w = abuf[n] / asum[b];
  atomicAdd(&rbuf[(size_t)b*64+o], w * out[(size_t)n*64+o]);
}

__global__ void k_qstar(const float* __restrict__ hl, const float* __restrict__ rbuf,
                        float* __restrict__ qstar){
  int t = blockIdx.x*256 + threadIdx.x;
  if (t >= NGRAPH*128) return;
  int b = t >> 7, c = t & 127;
  qstar[t] = (c < 64) ? hl[(size_t)b*64+c] : rbuf[(size_t)b*64 + c - 64];
}

__global__ void k_lin1(const float* __restrict__ qstar, const float* __restrict__ w,
                       const float* __restrict__ b, float* __restrict__ outp){
  __shared__ float qs[128];
  int bg = blockIdx.x, o = threadIdx.x;
  qs[o] = qstar[(size_t)bg*128+o];
  qs[64+o] = qstar[(size_t)bg*128+64+o];
  __syncthreads();
  float s = b[o];
  #pragma unroll 4
  for (int k = 0; k < 128; ++k) s += qs[k]*w[o*128+k];
  outp[(size_t)bg*64+o] = fmaxf(s, 0.f);
}

extern "C" void kernel_launch(void* const* d_in, const int* in_sizes, int n_in,
                              void* d_out, int out_size, void* d_ws, size_t ws_size,
                              hipStream_t stream){
  (void)in_sizes; (void)n_in; (void)out_size;
  const float* x      = (const float*)d_in[0];
  const float* eattr  = (const float*)d_in[1];
  const float* lin0w  = (const float*)d_in[2];
  const float* lin0b  = (const float*)d_in[3];
  const float* mlp1w  = (const float*)d_in[4];
  const float* mlp1b  = (const float*)d_in[5];
  const float* mlp2w  = (const float*)d_in[6];
  const float* mlp2b_ = (const float*)d_in[7];
  const float* rootw  = (const float*)d_in[8];
  const float* convb  = (const float*)d_in[9];
  const float* gwih   = (const float*)d_in[10];
  const float* gwhh   = (const float*)d_in[11];
  const float* gbih   = (const float*)d_in[12];
  const float* gbhh   = (const float*)d_in[13];
  const float* lwih   = (const float*)d_in[14];
  const float* lwhh   = (const float*)d_in[15];
  const float* lbih   = (const float*)d_in[16];
  const float* lbhh   = (const float*)d_in[17];
  const float* lin1w  = (const float*)d_in[18];
  const float* lin1b  = (const float*)d_in[19];
  const int*   eidx   = (const int*)d_in[20];
  const int*   batch  = (const int*)d_in[21];
  const int* srcp = eidx;
  const int* dstp = eidx + N_EDGES;

  char* ws = (char*)d_ws;
  size_t off = 0;
  auto take = [&](size_t bytes)->char*{
    char* p = ws + off; off = (off + bytes + 255) & ~(size_t)255; return p;
  };
  float* out   = (float*)take((size_t)N_NODES*64*4);
  unsigned short* outb = (unsigned short*)take((size_t)N_NODES*64*2);
  unsigned short* hidb = (unsigned short*)take((size_t)N_EDGES*128*2);
  float* agg   = (float*)take((size_t)N_NODES*64*4);
  float* deg   = (float*)take((size_t)N_NODES*4);
  unsigned short* w2b   = (unsigned short*)take((size_t)524288*2);
  unsigned short* rootb = (unsigned short*)take(4096*2);
  unsigned short* wihb  = (unsigned short*)take(12288*2);
  unsigned short* whhb  = (unsigned short*)take(12288*2);
  float* ebuf  = (float*)take((size_t)N_NODES*4);
  float* abuf  = (float*)take((size_t)N_NODES*4);
  char* z1 = take((size_t)NGRAPH*4 + NGRAPH*4 + (size_t)NGRAPH*64*4);
  unsigned* emaxu = (unsigned*)z1;
  float* asum = (float*)(z1 + NGRAPH*4);
  float* rbuf = (float*)(z1 + NGRAPH*8);
  size_t z1bytes = (size_t)NGRAPH*4 + NGRAPH*4 + (size_t)NGRAPH*64*4;
  char* z2 = take((size_t)NGRAPH*64*4*2 + (size_t)NGRAPH*128*4);
  float* hl = (float*)z2;
  float* cl = (float*)(z2 + (size_t)NGRAPH*64*4);
  float* qstar = (float*)(z2 + (size_t)NGRAPH*64*4*2);
  size_t z2bytes = (size_t)NGRAPH*64*4*2 + (size_t)NGRAPH*128*4;

  size_t remain = (ws_size > off) ? (ws_size - off) : 0;
  long long cap = (long long)(remain / ((size_t)4096*2));
  int chunk = (cap >= N_EDGES) ? N_EDGES : (int)(cap & ~63LL);
  if (chunk < 64) chunk = 64;
  unsigned short* ew = (unsigned short*)(ws + off);
  bool full = (chunk >= N_EDGES);

  hipMemsetAsync(deg, 0, (size_t)N_NODES*4, stream);
  hipMemsetAsync(z2, 0, z2bytes, stream);
  k_wcvt<<<2160,256,0,stream>>>(mlp2w, rootw, gwih, gwhh, w2b, rootb, wihb, whhb);
  k_lin0<<<12500,256,0,stream>>>(x, lin0w, lin0b, out, outb);
  k_mlp1<<<50000,256,0,stream>>>(eattr, mlp1w, mlp1b, hidb);
  k_deg<<<(N_EDGES+255)/256,256,0,stream>>>(dstp, deg);
  k_deginv<<<(N_NODES+255)/256,256,0,stream>>>(deg);
  if (full)
    k_mlp2<<<(N_EDGES+63)/64,256,0,stream>>>(hidb, w2b, mlp2b_, ew, 0, N_EDGES);

  for (int layer = 0; layer < 3; ++layer){
    hipMemsetAsync(agg, 0, (size_t)N_NODES*64*4, stream);
    if (full){
      k_msg<<<(N_EDGES+3)/4,256,0,stream>>>(out, ew, srcp, dstp, agg, 0, N_EDGES);
    } else {
      for (int e0 = 0; e0 < N_EDGES; e0 += chunk){
        int rows = (N_EDGES - e0 < chunk) ? (N_EDGES - e0) : chunk;
        k_mlp2<<<(rows+63)/64,256,0,stream>>>(hidb, w2b, mlp2b_, ew, e0, rows);
        k_msg<<<(rows+3)/4,256,0,stream>>>(out, ew, srcp, dstp, agg, e0, rows);
      }
    }
    k_update<<<(N_NODES+63)/64,256,0,stream>>>(out, outb, agg, deg, rootb, convb,
                                               wihb, whhb, gbih, gbhh);
  }

  for (int step = 0; step < 3; ++step){
    hipMemsetAsync(z1, 0, z1bytes, stream);
    k_lstm<<<NGRAPH,256,0,stream>>>(qstar, hl, cl, lwih, lwhh, lbih, lbhh);
    k_att_e<<<(N_NODES+3)/4,256,0,stream>>>(out, hl, batch, ebuf, emaxu);
    k_att_a<<<(N_NODES+255)/256,256,0,stream>>>(ebuf, batch, emaxu, abuf, asum);
    k_att_r<<<(N_NODES+3)/4,256,0,stream>>>(out, abuf, asum, batch, rbuf);
    k_qstar<<<(NGRAPH*128+255)/256,256,0,stream>>>(hl, rbuf, qstar);
  }
  k_lin1<<<NGRAPH,64,0,stream>>>(qstar, lin1w, lin1b, (float*)d_out);
}

// Round 6
// 2572.711 us; speedup vs baseline: 1.2504x; 1.2343x over previous
//
#include <hip/hip_runtime.h>
#include <hip/hip_bf16.h>
#include <stdint.h>

// QM9 encoder: lin0 -> (NNConv + GRU) x3 -> Set2Set x3 -> lin1
// N=50000, E=100000, D=64, B=2500.
// NO ew materialization. k_msgf fuses mlp2-GEMM (bf16 MFMA, C^T) with the
// per-edge contraction msg = out[src] @ ew and atomic scatter to agg.
// Set2Set = one block-per-graph kernel. 10 dispatches total.

#define N_NODES 50000
#define N_EDGES 100000
#define NGRAPH  2500
#define FIN     11
#define EATT    5

typedef __attribute__((ext_vector_type(8))) short short8;
typedef __attribute__((ext_vector_type(4))) float f32x4;

__device__ __forceinline__ short8 zero8(){ short8 z = {0,0,0,0,0,0,0,0}; return z; }

__device__ __forceinline__ unsigned short f2bf(float x){
  unsigned u = __float_as_uint(x);
  u += 0x7FFFu + ((u >> 16) & 1u);   // RNE
  return (unsigned short)(u >> 16);
}
__device__ __forceinline__ float sigm(float x){ return 1.0f/(1.0f+__expf(-x)); }

// ================= front: weight-cvt + lin0 + mlp1 + deg =================
#define FB_CVT   2160          // 552960 / 256
#define FB_LIN0  12500         // N*64 / 256
#define FB_MLP1  50000         // E*128 / 256
#define FB_DEG   391           // ceil(E/256)
__global__ void k_front(const float* __restrict__ x, const float* __restrict__ l0w,
        const float* __restrict__ l0b, float* __restrict__ out, unsigned short* __restrict__ outb,
        const float* __restrict__ ea, const float* __restrict__ m1w, const float* __restrict__ m1b,
        unsigned short* __restrict__ hidb, const int* __restrict__ dst, float* __restrict__ deg,
        const float* __restrict__ mlp2w, const float* __restrict__ rootw,
        const float* __restrict__ wih, const float* __restrict__ whh,
        unsigned short* __restrict__ w2b, unsigned short* __restrict__ rootb,
        unsigned short* __restrict__ wihb, unsigned short* __restrict__ whhb){
  int bb = blockIdx.x;
  if (bb < FB_CVT){
    int i = bb*256 + threadIdx.x;
    if (i < 524288) w2b[i] = f2bf(mlp2w[i]);
    else if (i < 528384) rootb[i-524288] = f2bf(rootw[i-524288]);
    else if (i < 540672) wihb[i-528384] = f2bf(wih[i-528384]);
    else                 whhb[i-540672] = f2bf(whh[i-540672]);
  } else if (bb < FB_CVT + FB_LIN0){
    int t = (bb-FB_CVT)*256 + threadIdx.x;
    int n = t >> 6, o = t & 63;
    float s = l0b[o];
    #pragma unroll
    for (int f = 0; f < FIN; ++f) s += x[n*FIN+f]*l0w[o*FIN+f];
    s = fmaxf(s, 0.f);
    out[(size_t)n*64+o] = s; outb[(size_t)n*64+o] = f2bf(s);
  } else if (bb < FB_CVT + FB_LIN0 + FB_MLP1){
    int t = (bb-FB_CVT-FB_LIN0)*256 + threadIdx.x;
    int e = t >> 7, j = t & 127;
    float s = m1b[j];
    #pragma unroll
    for (int a = 0; a < EATT; ++a) s += ea[e*EATT+a]*m1w[j*EATT+a];
    hidb[(size_t)e*128+j] = f2bf(fmaxf(s,0.f));
  } else {
    int e = (bb-FB_CVT-FB_LIN0-FB_MLP1)*256 + threadIdx.x;
    if (e < N_EDGES) atomicAdd(&deg[dst[e]], 1.0f);
  }
}

// ====== fused NNConv message: agg[dst_e] += out[src_e] @ (hid_e@W2^T+b2) ======
// block = 64 edges, 4 waves; wave covers i-range wave*16..+15 of the 64 input
// dims. C^T mfma(bfr, afr): lane holds edge = ms*16+lm, o = t*16+4g+r,
// i = wave*16+nt4. msg accumulated in regs over i, cross-wave reduced via
// LDS atomicAdd, scattered to agg with global atomics.
__global__ __launch_bounds__(256) void k_msgf(const unsigned short* __restrict__ hidb,
        const unsigned short* __restrict__ w2b, const float* __restrict__ b2,
        const float* __restrict__ out, const int* __restrict__ src,
        const int* __restrict__ dst, float* __restrict__ agg){
  __shared__ float buf[64*65];   // os[edge][i] (pad 65); later msg[edge][o]
  __shared__ int sidx[128];
  int mt = blockIdx.x;
  int tid = threadIdx.x;
  int wave = tid>>6, l = tid&63, lm = l&15, g = l>>4;
  if (tid < 64){
    int e = mt*64 + tid;
    sidx[tid]    = (e < N_EDGES) ? src[e] : -1;
    sidx[64+tid] = (e < N_EDGES) ? dst[e] : -1;
  }
  __syncthreads();
  { // stage out[src] rows: thread -> edge tid>>2, i-range (tid&3)*16..+15
    int el = tid>>2, i0 = (tid&3)*16;
    int sn = sidx[el];
    #pragma unroll
    for (int j = 0; j < 16; j += 4){
      float4 v;
      if (sn >= 0) v = *(const float4*)(out + (size_t)sn*64 + i0 + j);
      else { v.x = v.y = v.z = v.w = 0.f; }
      buf[el*65+i0+j]   = v.x; buf[el*65+i0+j+1] = v.y;
      buf[el*65+i0+j+2] = v.z; buf[el*65+i0+j+3] = v.w;
    }
  }
  short8 afr[4][4];
  #pragma unroll
  for (int ms = 0; ms < 4; ++ms){
    int r = mt*64 + ms*16 + lm;
    bool ok = (r < N_EDGES);
    #pragma unroll
    for (int kk = 0; kk < 4; ++kk)
      afr[ms][kk] = ok ? *(const short8*)(hidb + (size_t)r*128 + kk*32 + 8*g) : zero8();
  }
  __syncthreads();
  float msgacc[4][4][4];
  #pragma unroll
  for (int ms=0;ms<4;++ms){
    #pragma unroll
    for (int t=0;t<4;++t){
      #pragma unroll
      for (int r=0;r<4;++r) msgacc[ms][t][r] = 0.f;
    }
  }
  // osv snapshot for this wave's 16 i-values (read before buf is reused)
  float osv[4][16];
  #pragma unroll
  for (int ms=0;ms<4;++ms){
    #pragma unroll
    for (int q=0;q<16;++q) osv[ms][q] = buf[(ms*16+lm)*65 + wave*16 + q];
  }
  __syncthreads();
  { // zero msg buffer (reuse buf)
    int el = tid>>2, o0 = (tid&3)*16;
    #pragma unroll
    for (int j = 0; j < 16; ++j) buf[el*65+o0+j] = 0.f;
  }
  __syncthreads();
  for (int nt4 = 0; nt4 < 16; ++nt4){
    int nbase = wave*1024 + nt4*64;
    f32x4 acc[4][4];
    #pragma unroll
    for (int ms=0;ms<4;++ms){
      #pragma unroll
      for (int t=0;t<4;++t){ f32x4 z = {0.f,0.f,0.f,0.f}; acc[ms][t] = z; }
    }
    #pragma unroll
    for (int t = 0; t < 4; ++t){
      int n0 = nbase + t*16;
      #pragma unroll
      for (int kk = 0; kk < 4; ++kk){
        short8 bfr = *(const short8*)(w2b + (size_t)(n0+lm)*128 + kk*32 + 8*g);
        #pragma unroll
        for (int ms = 0; ms < 4; ++ms)
          acc[ms][t] = __builtin_amdgcn_mfma_f32_16x16x32_bf16(bfr, afr[ms][kk], acc[ms][t], 0,0,0);
      }
    }
    #pragma unroll
    for (int t = 0; t < 4; ++t){
      int n0 = nbase + t*16 + 4*g;
      float4 bv = *(const float4*)(b2 + n0);
      #pragma unroll
      for (int ms = 0; ms < 4; ++ms){
        float ov = osv[ms][nt4];
        msgacc[ms][t][0] += (acc[ms][t][0]+bv.x)*ov;
        msgacc[ms][t][1] += (acc[ms][t][1]+bv.y)*ov;
        msgacc[ms][t][2] += (acc[ms][t][2]+bv.z)*ov;
        msgacc[ms][t][3] += (acc[ms][t][3]+bv.w)*ov;
      }
    }
  }
  // cross-wave reduce: each wave owns distinct (edge,o) -> LDS atomics,
  // 4-way same-address collisions only across waves.
  #pragma unroll
  for (int ms=0;ms<4;++ms){
    int e_ = ms*16+lm;
    #pragma unroll
    for (int t=0;t<4;++t){
      #pragma unroll
      for (int r=0;r<4;++r){
        int o_ = t*16 + 4*g + r;
        atomicAdd(&buf[e_*65+o_], msgacc[ms][t][r]);
      }
    }
  }
  __syncthreads();
  {
    int el = tid>>2, o0 = (tid&3)*16;
    int dn = sidx[64+el];
    if (dn >= 0){
      float* ap = agg + (size_t)dn*64 + o0;
      #pragma unroll
      for (int j = 0; j < 16; ++j) atomicAdd(ap + j, buf[el*65+o0+j]);
    }
  }
}

// ---- fused: m = relu(agg/deg + out@root^T + cb); GRU(m, h=out) -> out ----
// also zeroes agg for the next layer.
__global__ __launch_bounds__(256) void k_update(float* __restrict__ out, unsigned short* __restrict__ outb,
        float* __restrict__ agg, const float* __restrict__ deg,
        const unsigned short* __restrict__ rootb, const float* __restrict__ convb,
        const unsigned short* __restrict__ wihb, const unsigned short* __restrict__ whhb,
        const float* __restrict__ bih, const float* __restrict__ bhh){
  __shared__ unsigned short ms_[4][1024];
  int wave = threadIdx.x >> 6;
  int l = threadIdx.x & 63;
  int lm = l & 15, g = l >> 4;
  int m0 = blockIdx.x*64 + wave*16;
  short8 ah[2];
  {
    int r = m0 + lm; bool ok = r < N_NODES;
    #pragma unroll
    for (int kk = 0; kk < 2; ++kk)
      ah[kk] = ok ? *(const short8*)(outb + (size_t)r*64 + kk*32 + 8*g) : zero8();
  }
  float dinv[4];
  #pragma unroll
  for (int i = 0; i < 4; ++i){
    int r = m0 + 4*g + i;
    dinv[i] = 1.0f / fmaxf((r < N_NODES) ? deg[r] : 1.f, 1.0f);
  }
  #pragma unroll
  for (int nt = 0; nt < 4; ++nt){
    f32x4 acc = {0.f,0.f,0.f,0.f};
    #pragma unroll
    for (int kk = 0; kk < 2; ++kk){
      short8 b = *(const short8*)(rootb + (size_t)(nt*16+lm)*64 + kk*32 + 8*g);
      acc = __builtin_amdgcn_mfma_f32_16x16x32_bf16(ah[kk], b, acc, 0,0,0);
    }
    int c = nt*16 + lm;
    #pragma unroll
    for (int i = 0; i < 4; ++i){
      int lr = 4*g + i, r = m0 + lr;
      float v = 0.f;
      if (r < N_NODES){
        size_t ix = (size_t)r*64 + c;
        v = fmaxf(acc[i] + agg[ix]*dinv[i] + convb[c], 0.f);
        agg[ix] = 0.f;
      }
      ms_[wave][(lr*64 + c) ^ ((lr&7)<<3)] = f2bf(v);
    }
  }
  __syncthreads();
  short8 am[2];
  #pragma unroll
  for (int kk = 0; kk < 2; ++kk)
    am[kk] = *(const short8*)(&ms_[wave][(lm*64 + kk*32 + 8*g) ^ ((lm&7)<<3)]);
  f32x4 accg[12], acch[12];
  #pragma unroll
  for (int nt = 0; nt < 12; ++nt){ f32x4 z = {0.f,0.f,0.f,0.f}; accg[nt]=z; acch[nt]=z; }
  #pragma unroll
  for (int nt = 0; nt < 12; ++nt){
    #pragma unroll
    for (int kk = 0; kk < 2; ++kk){
      short8 bg = *(const short8*)(wihb + (size_t)(nt*16+lm)*64 + kk*32 + 8*g);
      accg[nt] = __builtin_amdgcn_mfma_f32_16x16x32_bf16(am[kk], bg, accg[nt], 0,0,0);
      short8 bh = *(const short8*)(whhb + (size_t)(nt*16+lm)*64 + kk*32 + 8*g);
      acch[nt] = __builtin_amdgcn_mfma_f32_16x16x32_bf16(ah[kk], bh, acch[nt], 0,0,0);
    }
  }
  #pragma unroll
  for (int nt = 0; nt < 4; ++nt){
    int c = nt*16 + lm;
    #pragma unroll
    for (int i = 0; i < 4; ++i){
      int r = m0 + 4*g + i;
      if (r < N_NODES){
        float ir = accg[nt][i]   + bih[c],     hr = acch[nt][i]   + bhh[c];
        float iz = accg[nt+4][i] + bih[64+c],  hz = acch[nt+4][i] + bhh[64+c];
        float in_= accg[nt+8][i] + bih[128+c], hn = acch[nt+8][i] + bhh[128+c];
        float rr = sigm(ir+hr), zz = sigm(iz+hz);
        float nn = tanhf(in_ + rr*hn);
        float hp = out[(size_t)r*64+c];
        float hv = (1.f-zz)*nn + zz*hp;
        out[(size_t)r*64+c] = hv;
        outb[(size_t)r*64+c] = f2bf(hv);
      }
    }
  }
}

// ====== Set2Set (3 steps) + lin1, one block (64 thr) per graph ======
__global__ __launch_bounds__(64) void k_s2s(const float* __restrict__ out,
        const int* __restrict__ batch,
        const float* __restrict__ wih, const float* __restrict__ whh,
        const float* __restrict__ bih, const float* __restrict__ bhh,
        const float* __restrict__ w1, const float* __restrict__ b1,
        float* __restrict__ outp){
  int b = blockIdx.x, o = threadIdx.x;
  int s, e2;
  { int lo = 0, hi = N_NODES;
    while (lo < hi){ int m = (lo+hi)>>1; if (batch[m] < b) lo = m+1; else hi = m; }
    s = lo; hi = N_NODES;
    while (lo < hi){ int m = (lo+hi)>>1; if (batch[m] < b+1) lo = m+1; else hi = m; }
    e2 = lo;
  }
  int cnt = e2 - s;
  __shared__ float sq[128];   // q_star
  __shared__ float sh[64];    // hl
  __shared__ float se[512];   // per-node e then a
  __shared__ float sinv[1];
  float hl = 0.f, cl = 0.f;
  sq[o] = 0.f; sq[64+o] = 0.f; sh[o] = 0.f;
  __syncthreads();
  for (int step = 0; step < 3; ++step){
    float gi = bih[o]      + bhh[o];
    float gf = bih[64+o]   + bhh[64+o];
    float gg = bih[128+o]  + bhh[128+o];
    float go = bih[192+o]  + bhh[192+o];
    #pragma unroll 4
    for (int k = 0; k < 128; k += 4){
      float4 q4 = *(const float4*)(sq+k);
      float4 a4 = *(const float4*)(wih + (size_t)o*128 + k);
      float4 b4 = *(const float4*)(wih + (size_t)(64+o)*128 + k);
      float4 c4 = *(const float4*)(wih + (size_t)(128+o)*128 + k);
      float4 d4 = *(const float4*)(wih + (size_t)(192+o)*128 + k);
      gi += q4.x*a4.x + q4.y*a4.y + q4.z*a4.z + q4.w*a4.w;
      gf += q4.x*b4.x + q4.y*b4.y + q4.z*b4.z + q4.w*b4.w;
      gg += q4.x*c4.x + q4.y*c4.y + q4.z*c4.z + q4.w*c4.w;
      go += q4.x*d4.x + q4.y*d4.y + q4.z*d4.z + q4.w*d4.w;
    }
    #pragma unroll 4
    for (int k = 0; k < 64; k += 4){
      float4 h4 = *(const float4*)(sh+k);
      float4 a4 = *(const float4*)(whh + (size_t)o*64 + k);
      float4 b4 = *(const float4*)(whh + (size_t)(64+o)*64 + k);
      float4 c4 = *(const float4*)(whh + (size_t)(128+o)*64 + k);
      float4 d4 = *(const float4*)(whh + (size_t)(192+o)*64 + k);
      gi += h4.x*a4.x + h4.y*a4.y + h4.z*a4.z + h4.w*a4.w;
      gf += h4.x*b4.x + h4.y*b4.y + h4.z*b4.z + h4.w*b4.w;
      gg += h4.x*c4.x + h4.y*c4.y + h4.z*c4.z + h4.w*c4.w;
      go += h4.x*d4.x + h4.y*d4.y + h4.z*d4.z + h4.w*d4.w;
    }
    cl = sigm(gf)*cl + sigm(gi)*tanhf(gg);
    hl = sigm(go)*tanhf(cl);
    __syncthreads();
    sh[o] = hl; sq[o] = hl;
    __syncthreads();
    for (int j = o; j < cnt; j += 64){
      const float* op = out + (size_t)(s+j)*64;
      float d = 0.f;
      #pragma unroll 4
      for (int k = 0; k < 64; k += 4){
        float4 v  = *(const float4*)(op+k);
        float4 q4 = *(const float4*)(sq+k);
        d += v.x*q4.x + v.y*q4.y + v.z*q4.z + v.w*q4.w;
      }
      if (j < 512) se[j] = d;
    }
    __syncthreads();
    if (o == 0){
      float mx = -INFINITY;
      int c2 = cnt < 512 ? cnt : 512;
      for (int j = 0; j < c2; ++j) mx = fmaxf(mx, se[j]);
      float sm = 0.f;
      for (int j = 0; j < c2; ++j){ float a = __expf(se[j]-mx); se[j] = a; sm += a; }
      sinv[0] = (c2 > 0) ? 1.0f/sm : 0.f;
    }
    __syncthreads();
    float rv = 0.f;
    { int c2 = cnt < 512 ? cnt : 512;
      for (int j = 0; j < c2; ++j) rv += se[j]*out[(size_t)(s+j)*64 + o]; }
    rv *= sinv[0];
    __syncthreads();
    sq[64+o] = rv;
    __syncthreads();
  }
  float sacc = b1[o];
  #pragma unroll 4
  for (int k = 0; k < 128; k += 4){
    float4 q4 = *(const float4*)(sq+k);
    float4 w4 = *(const float4*)(w1 + (size_t)o*128 + k);
    sacc += q4.x*w4.x + q4.y*w4.y + q4.z*w4.z + q4.w*w4.w;
  }
  outp[(size_t)b*64 + o] = fmaxf(sacc, 0.f);
}

extern "C" void kernel_launch(void* const* d_in, const int* in_sizes, int n_in,
                              void* d_out, int out_size, void* d_ws, size_t ws_size,
                              hipStream_t stream){
  (void)in_sizes; (void)n_in; (void)out_size; (void)ws_size;
  const float* x      = (const float*)d_in[0];
  const float* eattr  = (const float*)d_in[1];
  const float* lin0w  = (const float*)d_in[2];
  const float* lin0b  = (const float*)d_in[3];
  const float* mlp1w  = (const float*)d_in[4];
  const float* mlp1b  = (const float*)d_in[5];
  const float* mlp2w  = (const float*)d_in[6];
  const float* mlp2b_ = (const float*)d_in[7];
  const float* rootw  = (const float*)d_in[8];
  const float* convb  = (const float*)d_in[9];
  const float* gwih   = (const float*)d_in[10];
  const float* gwhh   = (const float*)d_in[11];
  const float* gbih   = (const float*)d_in[12];
  const float* gbhh   = (const float*)d_in[13];
  const float* lwih   = (const float*)d_in[14];
  const float* lwhh   = (const float*)d_in[15];
  const float* lbih   = (const float*)d_in[16];
  const float* lbhh   = (const float*)d_in[17];
  const float* lin1w  = (const float*)d_in[18];
  const float* lin1b  = (const float*)d_in[19];
  const int*   eidx   = (const int*)d_in[20];
  const int*   batch  = (const int*)d_in[21];
  const int* srcp = eidx;
  const int* dstp = eidx + N_EDGES;

  char* ws = (char*)d_ws;
  size_t off = 0;
  auto take = [&](size_t bytes)->char*{
    char* p = ws + off; off = (off + bytes + 255) & ~(size_t)255; return p;
  };
  float* out           = (float*)take((size_t)N_NODES*64*4);
  unsigned short* outb = (unsigned short*)take((size_t)N_NODES*64*2);
  unsigned short* hidb = (unsigned short*)take((size_t)N_EDGES*128*2);
  float* agg           = (float*)take((size_t)N_NODES*64*4);
  float* deg           = (float*)take((size_t)N_NODES*4);
  unsigned short* w2b   = (unsigned short*)take((size_t)524288*2);
  unsigned short* rootb = (unsigned short*)take(4096*2);
  unsigned short* wihb  = (unsigned short*)take(12288*2);
  unsigned short* whhb  = (unsigned short*)take(12288*2);

  hipMemsetAsync(deg, 0, (size_t)N_NODES*4, stream);
  hipMemsetAsync(agg, 0, (size_t)N_NODES*64*4, stream);
  k_front<<<FB_CVT+FB_LIN0+FB_MLP1+FB_DEG,256,0,stream>>>(
      x, lin0w, lin0b, out, outb, eattr, mlp1w, mlp1b, hidb, dstp, deg,
      mlp2w, rootw, gwih, gwhh, w2b, rootb, wihb, whhb);
  for (int layer = 0; layer < 3; ++layer){
    k_msgf<<<(N_EDGES+63)/64,256,0,stream>>>(hidb, w2b, mlp2b_, out, srcp, dstp, agg);
    k_update<<<(N_NODES+63)/64,256,0,stream>>>(out, outb, agg, deg, rootb, convb,
                                               wihb, whhb, gbih, gbhh);
  }
  k_s2s<<<NGRAPH,64,0,stream>>>(out, batch, lwih, lwhh, lbih, lbhh, lin1w, lin1b,
                                (float*)d_out);
}

// Round 7
// 1837.078 us; speedup vs baseline: 1.7512x; 1.4004x over previous
//
#include <hip/hip_runtime.h>
#include <hip/hip_bf16.h>
#include <stdint.h>

// QM9 encoder: lin0 -> (NNConv + GRU) x3 -> Set2Set x3 -> lin1
// N=50000, E=100000, D=64, B=2500.
// k_msgf v2: wave owns 16 edges x all 64 i (low reg pressure, no spill);
// w2 tiles staged in LDS (double-buffered, XOR-swizzled), shared by 4 waves.

#define N_NODES 50000
#define N_EDGES 100000
#define NGRAPH  2500
#define FIN     11
#define EATT    5

typedef __attribute__((ext_vector_type(8))) short short8;
typedef __attribute__((ext_vector_type(4))) float f32x4;

__device__ __forceinline__ short8 zero8(){ short8 z = {0,0,0,0,0,0,0,0}; return z; }

__device__ __forceinline__ unsigned short f2bf(float x){
  unsigned u = __float_as_uint(x);
  u += 0x7FFFu + ((u >> 16) & 1u);   // RNE
  return (unsigned short)(u >> 16);
}
__device__ __forceinline__ float sigm(float x){ return 1.0f/(1.0f+__expf(-x)); }

// ================= front: weight-cvt + lin0 + mlp1 + deg =================
#define FB_CVT   2160          // 552960 / 256
#define FB_LIN0  12500         // N*64 / 256
#define FB_MLP1  50000         // E*128 / 256
#define FB_DEG   391           // ceil(E/256)
__global__ void k_front(const float* __restrict__ x, const float* __restrict__ l0w,
        const float* __restrict__ l0b, float* __restrict__ out, unsigned short* __restrict__ outb,
        const float* __restrict__ ea, const float* __restrict__ m1w, const float* __restrict__ m1b,
        unsigned short* __restrict__ hidb, const int* __restrict__ dst, float* __restrict__ deg,
        const float* __restrict__ mlp2w, const float* __restrict__ rootw,
        const float* __restrict__ wih, const float* __restrict__ whh,
        unsigned short* __restrict__ w2b, unsigned short* __restrict__ rootb,
        unsigned short* __restrict__ wihb, unsigned short* __restrict__ whhb){
  int bb = blockIdx.x;
  if (bb < FB_CVT){
    int i = bb*256 + threadIdx.x;
    if (i < 524288) w2b[i] = f2bf(mlp2w[i]);
    else if (i < 528384) rootb[i-524288] = f2bf(rootw[i-524288]);
    else if (i < 540672) wihb[i-528384] = f2bf(wih[i-528384]);
    else                 whhb[i-540672] = f2bf(whh[i-540672]);
  } else if (bb < FB_CVT + FB_LIN0){
    int t = (bb-FB_CVT)*256 + threadIdx.x;
    int n = t >> 6, o = t & 63;
    float s = l0b[o];
    #pragma unroll
    for (int f = 0; f < FIN; ++f) s += x[n*FIN+f]*l0w[o*FIN+f];
    s = fmaxf(s, 0.f);
    out[(size_t)n*64+o] = s; outb[(size_t)n*64+o] = f2bf(s);
  } else if (bb < FB_CVT + FB_LIN0 + FB_MLP1){
    int t = (bb-FB_CVT-FB_LIN0)*256 + threadIdx.x;
    int e = t >> 7, j = t & 127;
    float s = m1b[j];
    #pragma unroll
    for (int a = 0; a < EATT; ++a) s += ea[e*EATT+a]*m1w[j*EATT+a];
    hidb[(size_t)e*128+j] = f2bf(fmaxf(s,0.f));
  } else {
    int e = (bb-FB_CVT-FB_LIN0-FB_MLP1)*256 + threadIdx.x;
    if (e < N_EDGES) atomicAdd(&deg[dst[e]], 1.0f);
  }
}

// ====== fused NNConv message: agg[dst_e] += out[src_e] @ (hid_e@W2^T+b2) ======
// block = 64 edges, 4 waves; wave owns edges wave*16+lm (all 64 i, all 64 o).
// Per i: w2 rows i*64..i*64+63 staged in LDS (16KB tile, dbuf, XOR swizzle
// chunk^=(row&7)); 16 MFMA per wave (C^T operand order, verified r2 mapping:
// load tile-row t*16+lm -> output o=t*16+4g+r, edge=wave*16+lm).
__global__ __launch_bounds__(256) void k_msgf(const unsigned short* __restrict__ hidb,
        const unsigned short* __restrict__ w2b, const float* __restrict__ b2,
        const float* __restrict__ out, const int* __restrict__ src,
        const int* __restrict__ dst, float* __restrict__ agg){
  __shared__ unsigned short w2t[2][64*128];  // 2 x 16KB swizzled tiles
  __shared__ float os[64*65];                // out[src[e]][i]; later msg[e][o]
  __shared__ int sidx[128];
  int mt = blockIdx.x;
  int tid = threadIdx.x;
  int wave = tid>>6, l = tid&63, lm = l&15, g = l>>4;
  if (tid < 64){
    int e = mt*64 + tid;
    sidx[tid]    = (e < N_EDGES) ? src[e] : -1;
    sidx[64+tid] = (e < N_EDGES) ? dst[e] : -1;
  }
  __syncthreads();
  { // stage os[edge][i]
    int el = tid>>2, i0 = (tid&3)*16;
    int sn = sidx[el];
    #pragma unroll
    for (int j = 0; j < 16; j += 4){
      float4 v;
      if (sn >= 0) v = *(const float4*)(out + (size_t)sn*64 + i0 + j);
      else { v.x = v.y = v.z = v.w = 0.f; }
      os[el*65+i0+j]   = v.x; os[el*65+i0+j+1] = v.y;
      os[el*65+i0+j+2] = v.z; os[el*65+i0+j+3] = v.w;
    }
  }
  // afr: this wave's 16 edges (full k=128)
  short8 afr[4];
  {
    int e = mt*64 + wave*16 + lm;
    bool ok = (e < N_EDGES);
    #pragma unroll
    for (int kk = 0; kk < 4; ++kk)
      afr[kk] = ok ? *(const short8*)(hidb + (size_t)e*128 + kk*32 + 8*g) : zero8();
  }
  // staging geometry: thread -> tile row srow=tid>>2, 64B quarter sq=tid&3
  int srow = tid>>2, sq = tid&3, swz = srow & 7;
  { // prologue: tile i=0
    const uint4* gp = (const uint4*)(w2b + (size_t)srow*128 + sq*32);
    uint4 r0 = gp[0], r1 = gp[1], r2 = gp[2], r3 = gp[3];
    unsigned short* lb = &w2t[0][srow*128];
    int c0 = sq*4;
    *(uint4*)(lb + ((((c0+0)^swz))<<3)) = r0;
    *(uint4*)(lb + ((((c0+1)^swz))<<3)) = r1;
    *(uint4*)(lb + ((((c0+2)^swz))<<3)) = r2;
    *(uint4*)(lb + ((((c0+3)^swz))<<3)) = r3;
  }
  __syncthreads();
  float msgacc[4][4];
  #pragma unroll
  for (int t=0;t<4;++t){
    #pragma unroll
    for (int r=0;r<4;++r) msgacc[t][r] = 0.f;
  }
  int swzl = lm & 7;
  for (int i = 0; i < 64; ++i){
    uint4 r0, r1, r2, r3;
    if (i < 63){ // issue next-tile loads early
      const uint4* gp = (const uint4*)(w2b + (size_t)((i+1)*64 + srow)*128 + sq*32);
      r0 = gp[0]; r1 = gp[1]; r2 = gp[2]; r3 = gp[3];
    }
    const unsigned short* wt = w2t[i&1];
    f32x4 acc[4];
    #pragma unroll
    for (int t=0;t<4;++t){ f32x4 z = {0.f,0.f,0.f,0.f}; acc[t] = z; }
    #pragma unroll
    for (int t = 0; t < 4; ++t){
      #pragma unroll
      for (int kk = 0; kk < 4; ++kk){
        short8 bfr = *(const short8*)(wt + (t*16+lm)*128 + ((((kk<<2)+g)^swzl)<<3));
        acc[t] = __builtin_amdgcn_mfma_f32_16x16x32_bf16(bfr, afr[kk], acc[t], 0,0,0);
      }
    }
    float ov = os[(wave*16+lm)*65 + i];
    #pragma unroll
    for (int t = 0; t < 4; ++t){
      float4 bv = *(const float4*)(b2 + i*64 + t*16 + 4*g);
      msgacc[t][0] += (acc[t][0]+bv.x)*ov;
      msgacc[t][1] += (acc[t][1]+bv.y)*ov;
      msgacc[t][2] += (acc[t][2]+bv.z)*ov;
      msgacc[t][3] += (acc[t][3]+bv.w)*ov;
    }
    if (i < 63){ // write next tile (other buffer), then one barrier
      unsigned short* lb = &w2t[(i+1)&1][srow*128];
      int c0 = sq*4;
      *(uint4*)(lb + ((((c0+0)^swz))<<3)) = r0;
      *(uint4*)(lb + ((((c0+1)^swz))<<3)) = r1;
      *(uint4*)(lb + ((((c0+2)^swz))<<3)) = r2;
      *(uint4*)(lb + ((((c0+3)^swz))<<3)) = r3;
    }
    __syncthreads();
  }
  // msg -> LDS (each lane owns distinct (edge,o); plain stores)
  #pragma unroll
  for (int t = 0; t < 4; ++t){
    #pragma unroll
    for (int r = 0; r < 4; ++r)
      os[(wave*16+lm)*65 + t*16 + 4*g + r] = msgacc[t][r];
  }
  __syncthreads();
  { // scatter
    int el = tid>>2, o0 = (tid&3)*16;
    int dn = sidx[64+el];
    if (dn >= 0){
      float* ap = agg + (size_t)dn*64 + o0;
      #pragma unroll
      for (int j = 0; j < 16; ++j) atomicAdd(ap + j, os[el*65+o0+j]);
    }
  }
}

// ---- fused: m = relu(agg/deg + out@root^T + cb); GRU(m, h=out) -> out ----
// also zeroes agg for the next layer.
__global__ __launch_bounds__(256) void k_update(float* __restrict__ out, unsigned short* __restrict__ outb,
        float* __restrict__ agg, const float* __restrict__ deg,
        const unsigned short* __restrict__ rootb, const float* __restrict__ convb,
        const unsigned short* __restrict__ wihb, const unsigned short* __restrict__ whhb,
        const float* __restrict__ bih, const float* __restrict__ bhh){
  __shared__ unsigned short ms_[4][1024];
  int wave = threadIdx.x >> 6;
  int l = threadIdx.x & 63;
  int lm = l & 15, g = l >> 4;
  int m0 = blockIdx.x*64 + wave*16;
  short8 ah[2];
  {
    int r = m0 + lm; bool ok = r < N_NODES;
    #pragma unroll
    for (int kk = 0; kk < 2; ++kk)
      ah[kk] = ok ? *(const short8*)(outb + (size_t)r*64 + kk*32 + 8*g) : zero8();
  }
  float dinv[4];
  #pragma unroll
  for (int i = 0; i < 4; ++i){
    int r = m0 + 4*g + i;
    dinv[i] = 1.0f / fmaxf((r < N_NODES) ? deg[r] : 1.f, 1.0f);
  }
  #pragma unroll
  for (int nt = 0; nt < 4; ++nt){
    f32x4 acc = {0.f,0.f,0.f,0.f};
    #pragma unroll
    for (int kk = 0; kk < 2; ++kk){
      short8 b = *(const short8*)(rootb + (size_t)(nt*16+lm)*64 + kk*32 + 8*g);
      acc = __builtin_amdgcn_mfma_f32_16x16x32_bf16(ah[kk], b, acc, 0,0,0);
    }
    int c = nt*16 + lm;
    #pragma unroll
    for (int i = 0; i < 4; ++i){
      int lr = 4*g + i, r = m0 + lr;
      float v = 0.f;
      if (r < N_NODES){
        size_t ix = (size_t)r*64 + c;
        v = fmaxf(acc[i] + agg[ix]*dinv[i] + convb[c], 0.f);
        agg[ix] = 0.f;
      }
      ms_[wave][(lr*64 + c) ^ ((lr&7)<<3)] = f2bf(v);
    }
  }
  __syncthreads();
  short8 am[2];
  #pragma unroll
  for (int kk = 0; kk < 2; ++kk)
    am[kk] = *(const short8*)(&ms_[wave][(lm*64 + kk*32 + 8*g) ^ ((lm&7)<<3)]);
  f32x4 accg[12], acch[12];
  #pragma unroll
  for (int nt = 0; nt < 12; ++nt){ f32x4 z = {0.f,0.f,0.f,0.f}; accg[nt]=z; acch[nt]=z; }
  #pragma unroll
  for (int nt = 0; nt < 12; ++nt){
    #pragma unroll
    for (int kk = 0; kk < 2; ++kk){
      short8 bg = *(const short8*)(wihb + (size_t)(nt*16+lm)*64 + kk*32 + 8*g);
      accg[nt] = __builtin_amdgcn_mfma_f32_16x16x32_bf16(am[kk], bg, accg[nt], 0,0,0);
      short8 bh = *(const short8*)(whhb + (size_t)(nt*16+lm)*64 + kk*32 + 8*g);
      acch[nt] = __builtin_amdgcn_mfma_f32_16x16x32_bf16(ah[kk], bh, acch[nt], 0,0,0);
    }
  }
  #pragma unroll
  for (int nt = 0; nt < 4; ++nt){
    int c = nt*16 + lm;
    #pragma unroll
    for (int i = 0; i < 4; ++i){
      int r = m0 + 4*g + i;
      if (r < N_NODES){
        float ir = accg[nt][i]   + bih[c],     hr = acch[nt][i]   + bhh[c];
        float iz = accg[nt+4][i] + bih[64+c],  hz = acch[nt+4][i] + bhh[64+c];
        float in_= accg[nt+8][i] + bih[128+c], hn = acch[nt+8][i] + bhh[128+c];
        float rr = sigm(ir+hr), zz = sigm(iz+hz);
        float nn = tanhf(in_ + rr*hn);
        float hp = out[(size_t)r*64+c];
        float hv = (1.f-zz)*nn + zz*hp;
        out[(size_t)r*64+c] = hv;
        outb[(size_t)r*64+c] = f2bf(hv);
      }
    }
  }
}

// ====== Set2Set (3 steps) + lin1, one block (64 thr) per graph ======
__global__ __launch_bounds__(64) void k_s2s(const float* __restrict__ out,
        const int* __restrict__ batch,
        const float* __restrict__ wih, const float* __restrict__ whh,
        const float* __restrict__ bih, const float* __restrict__ bhh,
        const float* __restrict__ w1, const float* __restrict__ b1,
        float* __restrict__ outp){
  int b = blockIdx.x, o = threadIdx.x;
  int s, e2;
  { int lo = 0, hi = N_NODES;
    while (lo < hi){ int m = (lo+hi)>>1; if (batch[m] < b) lo = m+1; else hi = m; }
    s = lo; hi = N_NODES;
    while (lo < hi){ int m = (lo+hi)>>1; if (batch[m] < b+1) lo = m+1; else hi = m; }
    e2 = lo;
  }
  int cnt = e2 - s;
  __shared__ float sq[128];   // q_star
  __shared__ float sh[64];    // hl
  __shared__ float se[512];   // per-node e then a
  __shared__ float sinv[1];
  float hl = 0.f, cl = 0.f;
  sq[o] = 0.f; sq[64+o] = 0.f; sh[o] = 0.f;
  __syncthreads();
  for (int step = 0; step < 3; ++step){
    float gi = bih[o]      + bhh[o];
    float gf = bih[64+o]   + bhh[64+o];
    float gg = bih[128+o]  + bhh[128+o];
    float go = bih[192+o]  + bhh[192+o];
    #pragma unroll 4
    for (int k = 0; k < 128; k += 4){
      float4 q4 = *(const float4*)(sq+k);
      float4 a4 = *(const float4*)(wih + (size_t)o*128 + k);
      float4 b4 = *(const float4*)(wih + (size_t)(64+o)*128 + k);
      float4 c4 = *(const float4*)(wih + (size_t)(128+o)*128 + k);
      float4 d4 = *(const float4*)(wih + (size_t)(192+o)*128 + k);
      gi += q4.x*a4.x + q4.y*a4.y + q4.z*a4.z + q4.w*a4.w;
      gf += q4.x*b4.x + q4.y*b4.y + q4.z*b4.z + q4.w*b4.w;
      gg += q4.x*c4.x + q4.y*c4.y + q4.z*c4.z + q4.w*c4.w;
      go += q4.x*d4.x + q4.y*d4.y + q4.z*d4.z + q4.w*d4.w;
    }
    #pragma unroll 4
    for (int k = 0; k < 64; k += 4){
      float4 h4 = *(const float4*)(sh+k);
      float4 a4 = *(const float4*)(whh + (size_t)o*64 + k);
      float4 b4 = *(const float4*)(whh + (size_t)(64+o)*64 + k);
      float4 c4 = *(const float4*)(whh + (size_t)(128+o)*64 + k);
      float4 d4 = *(const float4*)(whh + (size_t)(192+o)*64 + k);
      gi += h4.x*a4.x + h4.y*a4.y + h4.z*a4.z + h4.w*a4.w;
      gf += h4.x*b4.x + h4.y*b4.y + h4.z*b4.z + h4.w*b4.w;
      gg += h4.x*c4.x + h4.y*c4.y + h4.z*c4.z + h4.w*c4.w;
      go += h4.x*d4.x + h4.y*d4.y + h4.z*d4.z + h4.w*d4.w;
    }
    cl = sigm(gf)*cl + sigm(gi)*tanhf(gg);
    hl = sigm(go)*tanhf(cl);
    __syncthreads();
    sh[o] = hl; sq[o] = hl;
    __syncthreads();
    for (int j = o; j < cnt; j += 64){
      const float* op = out + (size_t)(s+j)*64;
      float d = 0.f;
      #pragma unroll 4
      for (int k = 0; k < 64; k += 4){
        float4 v  = *(const float4*)(op+k);
        float4 q4 = *(const float4*)(sq+k);
        d += v.x*q4.x + v.y*q4.y + v.z*q4.z + v.w*q4.w;
      }
      if (j < 512) se[j] = d;
    }
    __syncthreads();
    if (o == 0){
      float mx = -INFINITY;
      int c2 = cnt < 512 ? cnt : 512;
      for (int j = 0; j < c2; ++j) mx = fmaxf(mx, se[j]);
      float sm = 0.f;
      for (int j = 0; j < c2; ++j){ float a = __expf(se[j]-mx); se[j] = a; sm += a; }
      sinv[0] = (c2 > 0) ? 1.0f/sm : 0.f;
    }
    __syncthreads();
    float rv = 0.f;
    { int c2 = cnt < 512 ? cnt : 512;
      for (int j = 0; j < c2; ++j) rv += se[j]*out[(size_t)(s+j)*64 + o]; }
    rv *= sinv[0];
    __syncthreads();
    sq[64+o] = rv;
    __syncthreads();
  }
  float sacc = b1[o];
  #pragma unroll 4
  for (int k = 0; k < 128; k += 4){
    float4 q4 = *(const float4*)(sq+k);
    float4 w4 = *(const float4*)(w1 + (size_t)o*128 + k);
    sacc += q4.x*w4.x + q4.y*w4.y + q4.z*w4.z + q4.w*w4.w;
  }
  outp[(size_t)b*64 + o] = fmaxf(sacc, 0.f);
}

extern "C" void kernel_launch(void* const* d_in, const int* in_sizes, int n_in,
                              void* d_out, int out_size, void* d_ws, size_t ws_size,
                              hipStream_t stream){
  (void)in_sizes; (void)n_in; (void)out_size; (void)ws_size;
  const float* x      = (const float*)d_in[0];
  const float* eattr  = (const float*)d_in[1];
  const float* lin0w  = (const float*)d_in[2];
  const float* lin0b  = (const float*)d_in[3];
  const float* mlp1w  = (const float*)d_in[4];
  const float* mlp1b  = (const float*)d_in[5];
  const float* mlp2w  = (const float*)d_in[6];
  const float* mlp2b_ = (const float*)d_in[7];
  const float* rootw  = (const float*)d_in[8];
  const float* convb  = (const float*)d_in[9];
  const float* gwih   = (const float*)d_in[10];
  const float* gwhh   = (const float*)d_in[11];
  const float* gbih   = (const float*)d_in[12];
  const float* gbhh   = (const float*)d_in[13];
  const float* lwih   = (const float*)d_in[14];
  const float* lwhh   = (const float*)d_in[15];
  const float* lbih   = (const float*)d_in[16];
  const float* lbhh   = (const float*)d_in[17];
  const float* lin1w  = (const float*)d_in[18];
  const float* lin1b  = (const float*)d_in[19];
  const int*   eidx   = (const int*)d_in[20];
  const int*   batch  = (const int*)d_in[21];
  const int* srcp = eidx;
  const int* dstp = eidx + N_EDGES;

  char* ws = (char*)d_ws;
  size_t off = 0;
  auto take = [&](size_t bytes)->char*{
    char* p = ws + off; off = (off + bytes + 255) & ~(size_t)255; return p;
  };
  float* out           = (float*)take((size_t)N_NODES*64*4);
  unsigned short* outb = (unsigned short*)take((size_t)N_NODES*64*2);
  unsigned short* hidb = (unsigned short*)take((size_t)N_EDGES*128*2);
  float* agg           = (float*)take((size_t)N_NODES*64*4);
  float* deg           = (float*)take((size_t)N_NODES*4);
  unsigned short* w2b   = (unsigned short*)take((size_t)524288*2);
  unsigned short* rootb = (unsigned short*)take(4096*2);
  unsigned short* wihb  = (unsigned short*)take(12288*2);
  unsigned short* whhb  = (unsigned short*)take(12288*2);

  hipMemsetAsync(deg, 0, (size_t)N_NODES*4, stream);
  hipMemsetAsync(agg, 0, (size_t)N_NODES*64*4, stream);
  k_front<<<FB_CVT+FB_LIN0+FB_MLP1+FB_DEG,256,0,stream>>>(
      x, lin0w, lin0b, out, outb, eattr, mlp1w, mlp1b, hidb, dstp, deg,
      mlp2w, rootw, gwih, gwhh, w2b, rootb, wihb, whhb);
  for (int layer = 0; layer < 3; ++layer){
    k_msgf<<<(N_EDGES+63)/64,256,0,stream>>>(hidb, w2b, mlp2b_, out, srcp, dstp, agg);
    k_update<<<(N_NODES+63)/64,256,0,stream>>>(out, outb, agg, deg, rootb, convb,
                                               wihb, whhb, gbih, gbhh);
  }
  k_s2s<<<NGRAPH,64,0,stream>>>(out, batch, lwih, lwhh, lbih, lbhh, lin1w, lin1b,
                                (float*)d_out);
}